// Round 1
// baseline (623.586 us; speedup 1.0000x reference)
//
#include <hip/hip_runtime.h>

#define N_NODES 50000
#define N_EDGES 600000

// ---------------- CSR build ----------------

__global__ void hist_kernel(const int* __restrict__ ei, int* __restrict__ cnt, int E) {
    int e = blockIdx.x * 256 + threadIdx.x;
    if (e < E) atomicAdd(&cnt[ei[E + e]], 1);
}

// phase 1: per-block (1024 elems) exclusive scan, block sums out
__global__ void scan1(const int* __restrict__ deg, int* __restrict__ out,
                      int* __restrict__ bsum, int n) {
    __shared__ int s[256];
    int t = threadIdx.x;
    int base = blockIdx.x * 1024 + t * 4;
    int v0 = (base + 0 < n) ? deg[base + 0] : 0;
    int v1 = (base + 1 < n) ? deg[base + 1] : 0;
    int v2 = (base + 2 < n) ? deg[base + 2] : 0;
    int v3 = (base + 3 < n) ? deg[base + 3] : 0;
    int tsum = v0 + v1 + v2 + v3;
    s[t] = tsum;
    __syncthreads();
    for (int off = 1; off < 256; off <<= 1) {
        int tmp = (t >= off) ? s[t - off] : 0;
        __syncthreads();
        s[t] += tmp;
        __syncthreads();
    }
    int excl = s[t] - tsum;
    if (base + 0 < n) out[base + 0] = excl;
    if (base + 1 < n) out[base + 1] = excl + v0;
    if (base + 2 < n) out[base + 2] = excl + v0 + v1;
    if (base + 3 < n) out[base + 3] = excl + v0 + v1 + v2;
    if (t == 255) bsum[blockIdx.x] = s[255];
}

// phase 2: serial exclusive scan of block sums (nb ~ 49, trivial)
__global__ void scan2(int* __restrict__ bsum, int nb) {
    if (threadIdx.x == 0 && blockIdx.x == 0) {
        int acc = 0;
        for (int i = 0; i < nb; ++i) { int v = bsum[i]; bsum[i] = acc; acc += v; }
    }
}

// phase 3: add block offsets in place; set off[n] = E
__global__ void scan3(int* __restrict__ off, const int* __restrict__ bsum, int n, int E) {
    int i = blockIdx.x * 256 + threadIdx.x;
    if (i < n) off[i] += bsum[i >> 10];
    if (i == n) off[n] = E;
}

// bucket scatter: per edge, compute slot in its dst bucket; stash src id and
// complex coefficient (cr, ci) = weight * (sim_r, sim_i)
__global__ void scatter_kernel(const int* __restrict__ ei, const float* __restrict__ w,
                               const float* __restrict__ sim, const int* __restrict__ off,
                               int* __restrict__ cnt, int* __restrict__ srcS,
                               float* __restrict__ crS, float* __restrict__ ciS, int E) {
    int e = blockIdx.x * 256 + threadIdx.x;
    if (e >= E) return;
    int s = ei[e], d = ei[E + e];
    int p = off[d] + atomicAdd(&cnt[d], 1);
    srcS[p] = s;
    float wt = w[e];
    crS[p] = wt * sim[2 * e];
    ciS[p] = wt * sim[2 * e + 1];
}

// ---------------- misc ----------------

// lwT[k*cout + j] = lw[j*cin + k]   (torch [out,in] -> [in,out])
__global__ void transpose_lw(const float* __restrict__ lw, float* __restrict__ lwT,
                             int cin, int cout) {
    int i = blockIdx.x * 256 + threadIdx.x;
    if (i >= cin * cout) return;
    int k = i / cout, j = i - k * cout;
    lwT[i] = lw[j * cin + k];
}

// ---------------- aggregation: one wave per node ----------------
// aggR[n,:] = sum_{e in CSR[n]} crS[e] * x[srcS[e],:]   (same for aggI with ciS)
template <int CIN>
__global__ __launch_bounds__(256) void agg_kernel(
    const float* __restrict__ x, const int* __restrict__ off,
    const int* __restrict__ srcS, const float* __restrict__ crS,
    const float* __restrict__ ciS, float* __restrict__ aggR,
    float* __restrict__ aggI, int n) {
    int wave = threadIdx.x >> 6;
    int lane = threadIdx.x & 63;
    int node = blockIdx.x * 4 + wave;
    if (node >= n) return;
    float ar0 = 0.f, ai0 = 0.f, ar1 = 0.f, ai1 = 0.f;
    int e0 = off[node], e1 = off[node + 1];
    for (int e = e0; e < e1; ++e) {
        int s = srcS[e];
        float cr = crS[e], ci = ciS[e];
        const float* xr = x + s * CIN;
        float v0 = (lane < CIN) ? xr[lane] : 0.f;
        ar0 += cr * v0;
        ai0 += ci * v0;
        if (CIN > 64) {
            float v1 = (lane + 64 < CIN) ? xr[lane + 64] : 0.f;
            ar1 += cr * v1;
            ai1 += ci * v1;
        }
    }
    if (lane < CIN) {
        aggR[node * CIN + lane] = ar0;
        aggI[node * CIN + lane] = ai0;
    }
    if (CIN > 64 && lane + 64 < CIN) {
        aggR[node * CIN + lane + 64] = ar1;
        aggI[node * CIN + lane + 64] = ai1;
    }
}

// ---------------- fused GEMM + bias + relu ----------------
// out[n,j] = relu( sum_k aggR[n,k]*wr[k,j] - aggI[n,k]*wi[k,j] + x[n,k]*lwT[k,j]
//                  + cb[j] + lb[j] )
// Tile: 64 nodes x COUT cols per block (256 threads). Each thread: 8 cols x NPT nodes.
template <int CIN, int COUT>
__global__ __launch_bounds__(256) void gemm_kernel(
    const float* __restrict__ aggR, const float* __restrict__ aggI,
    const float* __restrict__ x, const float* __restrict__ wr,
    const float* __restrict__ wi, const float* __restrict__ lwT,
    const float* __restrict__ cb, const float* __restrict__ lb,
    float* __restrict__ out, int n) {
    constexpr int KC = 16;
    constexpr int CT = COUT / 8;    // threads along cols (16 or 4)
    constexpr int NTt = 256 / CT;   // threads along nodes (16 or 64)
    constexpr int NPT = 64 / NTt;   // nodes per thread (4 or 1)
    constexpr int AP = 68;          // padded A-tile stride (mult of 4, breaks 64-stride banks)
    __shared__ float sA[KC][AP];
    __shared__ float sW[KC][COUT];

    int t = threadIdx.x;
    int jc = (t % CT) * 8;
    int ng = t / CT;
    int node0 = blockIdx.x * 64;

    float acc[NPT][8];
    float bias[8];
#pragma unroll
    for (int j = 0; j < 8; ++j) bias[j] = cb[jc + j] + lb[jc + j];
#pragma unroll
    for (int i = 0; i < NPT; ++i)
#pragma unroll
        for (int j = 0; j < 8; ++j) acc[i][j] = bias[j];

    const float* Aparts[3] = {aggR, aggI, x};
    const float* Wparts[3] = {wr, wi, lwT};

    for (int part = 0; part < 3; ++part) {
        const float* __restrict__ A = Aparts[part];
        const float* __restrict__ W = Wparts[part];
        float sgn = (part == 1) ? -1.f : 1.f;
        for (int kc = 0; kc < CIN; kc += KC) {
            __syncthreads();
            // stage A tile transposed: sA[k][node]
            for (int idx = t; idx < 64 * KC; idx += 256) {
                int nn = idx >> 4;
                int kk = idx & 15;
                int node = node0 + nn;
                int k = kc + kk;
                float v = 0.f;
                if (node < n && k < CIN) v = A[node * CIN + k];
                sA[kk][nn] = v;
            }
            // stage W tile (sign folded): sW[k][j]
            for (int idx = t; idx < KC * COUT; idx += 256) {
                int kk = idx / COUT;
                int jj = idx - kk * COUT;
                int k = kc + kk;
                float v = 0.f;
                if (k < CIN) v = W[k * COUT + jj];
                sW[kk][jj] = sgn * v;
            }
            __syncthreads();
#pragma unroll
            for (int kk = 0; kk < KC; ++kk) {
                float4 w0 = *(const float4*)&sW[kk][jc];
                float4 w1 = *(const float4*)&sW[kk][jc + 4];
                float a[NPT];
#pragma unroll
                for (int i = 0; i < NPT; ++i) a[i] = sA[kk][ng * NPT + i];
#pragma unroll
                for (int i = 0; i < NPT; ++i) {
                    acc[i][0] += a[i] * w0.x;
                    acc[i][1] += a[i] * w0.y;
                    acc[i][2] += a[i] * w0.z;
                    acc[i][3] += a[i] * w0.w;
                    acc[i][4] += a[i] * w1.x;
                    acc[i][5] += a[i] * w1.y;
                    acc[i][6] += a[i] * w1.z;
                    acc[i][7] += a[i] * w1.w;
                }
            }
        }
    }

#pragma unroll
    for (int i = 0; i < NPT; ++i) {
        int node = node0 + ng * NPT + i;
        if (node < n) {
#pragma unroll
            for (int j = 0; j < 8; ++j) {
                float v = acc[i][j];
                out[node * COUT + jc + j] = v > 0.f ? v : 0.f;
            }
        }
    }
}

// ---------------- launch ----------------

extern "C" void kernel_launch(void* const* d_in, const int* in_sizes, int n_in,
                              void* d_out, int out_size, void* d_ws, size_t ws_size,
                              hipStream_t stream) {
    const float* x0  = (const float*)d_in[0];
    const int*   ei  = (const int*)d_in[1];
    const float* wgt = (const float*)d_in[2];
    const float* sim = (const float*)d_in[3];
    const float *wr[3], *wi[3], *cb[3], *lw[3], *lb[3];
    for (int l = 0; l < 3; ++l) {
        wr[l] = (const float*)d_in[4 + 5 * l];
        wi[l] = (const float*)d_in[5 + 5 * l];
        cb[l] = (const float*)d_in[6 + 5 * l];
        lw[l] = (const float*)d_in[7 + 5 * l];
        lb[l] = (const float*)d_in[8 + 5 * l];
    }

    char* p = (char*)d_ws;
    auto alloc = [&](size_t bytes) -> void* {
        void* r = p;
        p += (bytes + 255) & ~(size_t)255;
        return r;
    };
    int*   off  = (int*)alloc((N_NODES + 1) * 4);
    int*   cnt  = (int*)alloc(N_NODES * 4);
    int*   bsum = (int*)alloc(256);
    int*   srcS = (int*)alloc(N_EDGES * 4);
    float* crS  = (float*)alloc(N_EDGES * 4);
    float* ciS  = (float*)alloc(N_EDGES * 4);
    float* lwT0 = (float*)alloc(75 * 128 * 4);
    float* lwT1 = (float*)alloc(128 * 128 * 4);
    float* lwT2 = (float*)alloc(128 * 32 * 4);
    float* aggR = (float*)alloc((size_t)N_NODES * 128 * 4);
    float* aggI = (float*)alloc((size_t)N_NODES * 128 * 4);
    float* h1   = (float*)alloc((size_t)N_NODES * 128 * 4);
    float* h2   = (float*)alloc((size_t)N_NODES * 128 * 4);
    float* outp = (float*)d_out;

    // CSR build
    hipMemsetAsync(cnt, 0, N_NODES * 4, stream);
    hist_kernel<<<(N_EDGES + 255) / 256, 256, 0, stream>>>(ei, cnt, N_EDGES);
    int nb = (N_NODES + 1023) / 1024;
    scan1<<<nb, 256, 0, stream>>>(cnt, off, bsum, N_NODES);
    scan2<<<1, 64, 0, stream>>>(bsum, nb);
    scan3<<<(N_NODES + 1 + 255) / 256, 256, 0, stream>>>(off, bsum, N_NODES, N_EDGES);
    hipMemsetAsync(cnt, 0, N_NODES * 4, stream);
    scatter_kernel<<<(N_EDGES + 255) / 256, 256, 0, stream>>>(ei, wgt, sim, off, cnt,
                                                              srcS, crS, ciS, N_EDGES);
    // weight transposes
    transpose_lw<<<(75 * 128 + 255) / 256, 256, 0, stream>>>(lw[0], lwT0, 75, 128);
    transpose_lw<<<(128 * 128 + 255) / 256, 256, 0, stream>>>(lw[1], lwT1, 128, 128);
    transpose_lw<<<(128 * 32 + 255) / 256, 256, 0, stream>>>(lw[2], lwT2, 128, 32);

    int agrid = (N_NODES + 3) / 4;
    int ggrid = (N_NODES + 63) / 64;

    // layer 0: x0 (75) -> h1 (128)
    agg_kernel<75><<<agrid, 256, 0, stream>>>(x0, off, srcS, crS, ciS, aggR, aggI, N_NODES);
    gemm_kernel<75, 128><<<ggrid, 256, 0, stream>>>(aggR, aggI, x0, wr[0], wi[0], lwT0,
                                                    cb[0], lb[0], h1, N_NODES);
    // layer 1: h1 (128) -> h2 (128)
    agg_kernel<128><<<agrid, 256, 0, stream>>>(h1, off, srcS, crS, ciS, aggR, aggI, N_NODES);
    gemm_kernel<128, 128><<<ggrid, 256, 0, stream>>>(aggR, aggI, h1, wr[1], wi[1], lwT1,
                                                     cb[1], lb[1], h2, N_NODES);
    // layer 2: h2 (128) -> out (32)
    agg_kernel<128><<<agrid, 256, 0, stream>>>(h2, off, srcS, crS, ciS, aggR, aggI, N_NODES);
    gemm_kernel<128, 32><<<ggrid, 256, 0, stream>>>(aggR, aggI, h2, wr[2], wi[2], lwT2,
                                                    cb[2], lb[2], outp, N_NODES);
}

// Round 2
// 361.177 us; speedup vs baseline: 1.7265x; 1.7265x over previous
//
#include <hip/hip_runtime.h>

#define N_NODES 50000
#define N_EDGES 600000

using bf16x8 = __attribute__((ext_vector_type(8))) short;
using f32x4  = __attribute__((ext_vector_type(4))) float;
typedef unsigned short ushort_t;
typedef unsigned int   uint32_tt;

__device__ __forceinline__ unsigned short f2bf(float f) {
    union { float f; unsigned int u; } v; v.f = f;
    unsigned int u = v.u;
    return (unsigned short)((u + 0x7fffu + ((u >> 16) & 1u)) >> 16);  // RNE
}
__device__ __forceinline__ float bf2f(unsigned int h16) {
    union { unsigned int u; float f; } v; v.u = h16 << 16;
    return v.f;
}

// ---------------- CSR build ----------------

__global__ void hist_kernel(const int* __restrict__ ei, int* __restrict__ cnt, int E) {
    int e = blockIdx.x * 256 + threadIdx.x;
    if (e < E) atomicAdd(&cnt[ei[E + e]], 1);
}

__global__ void scan1(const int* __restrict__ deg, int* __restrict__ out,
                      int* __restrict__ bsum, int n) {
    __shared__ int s[256];
    int t = threadIdx.x;
    int base = blockIdx.x * 1024 + t * 4;
    int v0 = (base + 0 < n) ? deg[base + 0] : 0;
    int v1 = (base + 1 < n) ? deg[base + 1] : 0;
    int v2 = (base + 2 < n) ? deg[base + 2] : 0;
    int v3 = (base + 3 < n) ? deg[base + 3] : 0;
    int tsum = v0 + v1 + v2 + v3;
    s[t] = tsum;
    __syncthreads();
    for (int off = 1; off < 256; off <<= 1) {
        int tmp = (t >= off) ? s[t - off] : 0;
        __syncthreads();
        s[t] += tmp;
        __syncthreads();
    }
    int excl = s[t] - tsum;
    if (base + 0 < n) out[base + 0] = excl;
    if (base + 1 < n) out[base + 1] = excl + v0;
    if (base + 2 < n) out[base + 2] = excl + v0 + v1;
    if (base + 3 < n) out[base + 3] = excl + v0 + v1 + v2;
    if (t == 255) bsum[blockIdx.x] = s[255];
}

__global__ void scan2(int* __restrict__ bsum, int nb) {
    if (threadIdx.x == 0 && blockIdx.x == 0) {
        int acc = 0;
        for (int i = 0; i < nb; ++i) { int v = bsum[i]; bsum[i] = acc; acc += v; }
    }
}

__global__ void scan3(int* __restrict__ off, const int* __restrict__ bsum, int n, int E) {
    int i = blockIdx.x * 256 + threadIdx.x;
    if (i < n) off[i] += bsum[i >> 10];
    if (i == n) off[n] = E;
}

__global__ void scatter_kernel(const int* __restrict__ ei, const float* __restrict__ w,
                               const float* __restrict__ sim, const int* __restrict__ off,
                               int* __restrict__ cnt, int* __restrict__ srcS,
                               float* __restrict__ crS, float* __restrict__ ciS, int E) {
    int e = blockIdx.x * 256 + threadIdx.x;
    if (e >= E) return;
    int s = ei[e], d = ei[E + e];
    int p = off[d] + atomicAdd(&cnt[d], 1);
    srcS[p] = s;
    float wt = w[e];
    crS[p] = wt * sim[2 * e];
    ciS[p] = wt * sim[2 * e + 1];
}

// ---------------- prep: x -> bf16 padded [N][96]; weight pack ----------------

__global__ void convert_x(const float* __restrict__ x0, unsigned short* __restrict__ xb, int n) {
    int i = blockIdx.x * 256 + threadIdx.x;
    if (i >= n * 96) return;
    int r = i / 96, c = i - r * 96;
    xb[i] = (c < 75) ? f2bf(x0[r * 75 + c]) : (unsigned short)0;
}

// BT[n][part*CINP + k] = {wr[k][n], -wi[k][n], lw[n][k]}  (bf16, zero-padded k>=CIN)
__global__ void build_bt(const float* __restrict__ wr, const float* __restrict__ wi,
                         const float* __restrict__ lw, unsigned short* __restrict__ BT,
                         int CIN, int CINP, int COUT) {
    int KTOT = 3 * CINP;
    int i = blockIdx.x * 256 + threadIdx.x;
    if (i >= COUT * KTOT) return;
    int nn = i / KTOT, k = i - nn * KTOT;
    int part = k / CINP, kk = k - part * CINP;
    float v = 0.f;
    if (kk < CIN) {
        if (part == 0)      v = wr[kk * COUT + nn];
        else if (part == 1) v = -wi[kk * COUT + nn];
        else                v = lw[nn * CIN + kk];
    }
    BT[i] = f2bf(v);
}

// ---------------- aggregation (bf16 in/out, fp32 accum): one wave per node ----
template <int CU2>  // uint32s per feature row (= CINP/2)
__global__ __launch_bounds__(256) void agg_bf16(
    const uint32_tt* __restrict__ x, const int* __restrict__ off,
    const int* __restrict__ srcS, const float* __restrict__ crS,
    const float* __restrict__ ciS, uint32_tt* __restrict__ aggR,
    uint32_tt* __restrict__ aggI, int n) {
    int wave = threadIdx.x >> 6;
    int lane = threadIdx.x & 63;
    int node = blockIdx.x * 4 + wave;
    if (node >= n) return;
    float arl = 0.f, arh = 0.f, ail = 0.f, aih = 0.f;
    int e0 = off[node], e1 = off[node + 1];
    bool act = lane < CU2;
    int e = e0;
    for (; e + 1 < e1; e += 2) {
        int s0 = srcS[e], s1 = srcS[e + 1];
        float cr0 = crS[e], ci0 = ciS[e];
        float cr1 = crS[e + 1], ci1 = ciS[e + 1];
        uint32_tt w0 = act ? x[(size_t)s0 * CU2 + lane] : 0u;
        uint32_tt w1 = act ? x[(size_t)s1 * CU2 + lane] : 0u;
        float l0 = bf2f(w0 & 0xffffu), h0 = bf2f(w0 >> 16);
        float l1 = bf2f(w1 & 0xffffu), h1 = bf2f(w1 >> 16);
        arl += cr0 * l0; arh += cr0 * h0;
        ail += ci0 * l0; aih += ci0 * h0;
        arl += cr1 * l1; arh += cr1 * h1;
        ail += ci1 * l1; aih += ci1 * h1;
    }
    if (e < e1) {
        int s0 = srcS[e];
        float cr0 = crS[e], ci0 = ciS[e];
        uint32_tt w0 = act ? x[(size_t)s0 * CU2 + lane] : 0u;
        float l0 = bf2f(w0 & 0xffffu), h0 = bf2f(w0 >> 16);
        arl += cr0 * l0; arh += cr0 * h0;
        ail += ci0 * l0; aih += ci0 * h0;
    }
    if (act) {
        aggR[(size_t)node * CU2 + lane] = (uint32_tt)f2bf(arl) | ((uint32_tt)f2bf(arh) << 16);
        aggI[(size_t)node * CU2 + lane] = (uint32_tt)f2bf(ail) | ((uint32_tt)f2bf(aih) << 16);
    }
}

// ---------------- bf16 MFMA GEMM: out = relu([aggR|aggI|x] @ BT^T + cb + lb) --
// Block: 256 threads = 4 waves (WM x WN). Block tile BM x COUT.
// Wave tile (MT*16) x (NT*16). K in chunks of 32, 16x16x32 bf16 MFMA.
template <int CINP, int COUT, int BM, int WM, int WN, int MT, int NT, bool OUT_BF16>
__global__ __launch_bounds__(256) void gemm_mfma(
    const unsigned short* __restrict__ A0, const unsigned short* __restrict__ A1,
    const unsigned short* __restrict__ A2, const unsigned short* __restrict__ BT,
    const float* __restrict__ cb, const float* __restrict__ lb,
    void* __restrict__ outv, int n) {
    constexpr int PK = 40;              // padded k-stride (bf16): 80B rows -> 2-way banks
    constexpr int KTOT = 3 * CINP;
    constexpr int NCH = KTOT / 32;      // K chunks
    constexpr int CPP = CINP / 32;      // chunks per part
    __shared__ unsigned short sA[BM][PK];
    __shared__ unsigned short sB[COUT][PK];

    int t = threadIdx.x;
    int lane = t & 63, wave = t >> 6;
    int wm = wave / WN, wn = wave % WN;
    int ml = lane & 15, kh = lane >> 4;   // kh in [0,4)
    int node0 = blockIdx.x * BM;

    const unsigned short* Asrc[3] = {A0, A1, A2};

    f32x4 acc[MT][NT];
#pragma unroll
    for (int mt = 0; mt < MT; ++mt)
#pragma unroll
        for (int nt = 0; nt < NT; ++nt) acc[mt][nt] = (f32x4){0.f, 0.f, 0.f, 0.f};

    for (int c = 0; c < NCH; ++c) {
        int part = c / CPP;
        int kk = (c - part * CPP) * 32;
        const unsigned short* __restrict__ Ap = Asrc[part];
        __syncthreads();
        // stage A tile: BM rows x 32 bf16 (4 x 16B per row)
#pragma unroll
        for (int i = t; i < BM * 4; i += 256) {
            int r = i >> 2, q = i & 3;
            int node = node0 + r;
            if (node >= n) node = n - 1;  // clamp: garbage rows never written out
            *(uint4*)&sA[r][q * 8] =
                *(const uint4*)(Ap + (size_t)node * CINP + kk + q * 8);
        }
        // stage B tile: COUT rows x 32 bf16
#pragma unroll
        for (int i = t; i < COUT * 4; i += 256) {
            int r = i >> 2, q = i & 3;
            *(uint4*)&sB[r][q * 8] =
                *(const uint4*)(BT + (size_t)r * KTOT + c * 32 + q * 8);
        }
        __syncthreads();
        bf16x8 af[MT], bfr[NT];
#pragma unroll
        for (int mt = 0; mt < MT; ++mt)
            af[mt] = *(const bf16x8*)&sA[wm * (MT * 16) + mt * 16 + ml][kh * 8];
#pragma unroll
        for (int nt = 0; nt < NT; ++nt)
            bfr[nt] = *(const bf16x8*)&sB[wn * (NT * 16) + nt * 16 + ml][kh * 8];
#pragma unroll
        for (int mt = 0; mt < MT; ++mt)
#pragma unroll
            for (int nt = 0; nt < NT; ++nt)
                acc[mt][nt] = __builtin_amdgcn_mfma_f32_16x16x32_bf16(
                    af[mt], bfr[nt], acc[mt][nt], 0, 0, 0);
    }

    // epilogue: C/D layout col=lane&15, row=(lane>>4)*4+reg  [m89-verified]
    int row0 = kh * 4;
#pragma unroll
    for (int nt = 0; nt < NT; ++nt) {
        int col = wn * (NT * 16) + nt * 16 + ml;
        float bias = cb[col] + lb[col];
#pragma unroll
        for (int mt = 0; mt < MT; ++mt) {
#pragma unroll
            for (int r = 0; r < 4; ++r) {
                int node = node0 + wm * (MT * 16) + mt * 16 + row0 + r;
                if (node < n) {
                    float v = acc[mt][nt][r] + bias;
                    v = v > 0.f ? v : 0.f;
                    if (OUT_BF16)
                        ((unsigned short*)outv)[(size_t)node * COUT + col] = f2bf(v);
                    else
                        ((float*)outv)[(size_t)node * COUT + col] = v;
                }
            }
        }
    }
}

// ---------------- launch ----------------

extern "C" void kernel_launch(void* const* d_in, const int* in_sizes, int n_in,
                              void* d_out, int out_size, void* d_ws, size_t ws_size,
                              hipStream_t stream) {
    const float* x0  = (const float*)d_in[0];
    const int*   ei  = (const int*)d_in[1];
    const float* wgt = (const float*)d_in[2];
    const float* sim = (const float*)d_in[3];
    const float *wr[3], *wi[3], *cb[3], *lw[3], *lb[3];
    for (int l = 0; l < 3; ++l) {
        wr[l] = (const float*)d_in[4 + 5 * l];
        wi[l] = (const float*)d_in[5 + 5 * l];
        cb[l] = (const float*)d_in[6 + 5 * l];
        lw[l] = (const float*)d_in[7 + 5 * l];
        lb[l] = (const float*)d_in[8 + 5 * l];
    }

    char* p = (char*)d_ws;
    auto alloc = [&](size_t bytes) -> void* {
        void* r = p;
        p += (bytes + 255) & ~(size_t)255;
        return r;
    };
    int*   off  = (int*)alloc((N_NODES + 1) * 4);
    int*   cnt  = (int*)alloc(N_NODES * 4);
    int*   bsum = (int*)alloc(256);
    int*   srcS = (int*)alloc(N_EDGES * 4);
    float* crS  = (float*)alloc(N_EDGES * 4);
    float* ciS  = (float*)alloc(N_EDGES * 4);
    unsigned short* xb    = (unsigned short*)alloc((size_t)N_NODES * 96 * 2);
    unsigned short* aggRb = (unsigned short*)alloc((size_t)N_NODES * 128 * 2);
    unsigned short* aggIb = (unsigned short*)alloc((size_t)N_NODES * 128 * 2);
    unsigned short* h1b   = (unsigned short*)alloc((size_t)N_NODES * 128 * 2);
    unsigned short* h2b   = (unsigned short*)alloc((size_t)N_NODES * 128 * 2);
    unsigned short* BT0   = (unsigned short*)alloc((size_t)128 * 288 * 2);
    unsigned short* BT1   = (unsigned short*)alloc((size_t)128 * 384 * 2);
    unsigned short* BT2   = (unsigned short*)alloc((size_t)32 * 384 * 2);
    float* outp = (float*)d_out;

    // CSR build
    hipMemsetAsync(cnt, 0, N_NODES * 4, stream);
    hist_kernel<<<(N_EDGES + 255) / 256, 256, 0, stream>>>(ei, cnt, N_EDGES);
    int nb = (N_NODES + 1023) / 1024;
    scan1<<<nb, 256, 0, stream>>>(cnt, off, bsum, N_NODES);
    scan2<<<1, 64, 0, stream>>>(bsum, nb);
    scan3<<<(N_NODES + 1 + 255) / 256, 256, 0, stream>>>(off, bsum, N_NODES, N_EDGES);
    hipMemsetAsync(cnt, 0, N_NODES * 4, stream);
    scatter_kernel<<<(N_EDGES + 255) / 256, 256, 0, stream>>>(ei, wgt, sim, off, cnt,
                                                              srcS, crS, ciS, N_EDGES);
    // prep
    convert_x<<<(N_NODES * 96 + 255) / 256, 256, 0, stream>>>(x0, xb, N_NODES);
    build_bt<<<(128 * 288 + 255) / 256, 256, 0, stream>>>(wr[0], wi[0], lw[0], BT0, 75, 96, 128);
    build_bt<<<(128 * 384 + 255) / 256, 256, 0, stream>>>(wr[1], wi[1], lw[1], BT1, 128, 128, 128);
    build_bt<<<(32 * 384 + 255) / 256, 256, 0, stream>>>(wr[2], wi[2], lw[2], BT2, 128, 128, 32);

    int agrid = (N_NODES + 3) / 4;

    // layer 0: xb [N,96] -> h1b [N,128]
    agg_bf16<48><<<agrid, 256, 0, stream>>>((const uint32_tt*)xb, off, srcS, crS, ciS,
                                            (uint32_tt*)aggRb, (uint32_tt*)aggIb, N_NODES);
    gemm_mfma<96, 128, 64, 2, 2, 2, 4, true>
        <<<(N_NODES + 63) / 64, 256, 0, stream>>>(aggRb, aggIb, xb, BT0, cb[0], lb[0],
                                                  h1b, N_NODES);
    // layer 1: h1b [N,128] -> h2b [N,128]
    agg_bf16<64><<<agrid, 256, 0, stream>>>((const uint32_tt*)h1b, off, srcS, crS, ciS,
                                            (uint32_tt*)aggRb, (uint32_tt*)aggIb, N_NODES);
    gemm_mfma<128, 128, 64, 2, 2, 2, 4, true>
        <<<(N_NODES + 63) / 64, 256, 0, stream>>>(aggRb, aggIb, h1b, BT1, cb[1], lb[1],
                                                  h2b, N_NODES);
    // layer 2: h2b [N,128] -> out [N,32] fp32
    agg_bf16<64><<<agrid, 256, 0, stream>>>((const uint32_tt*)h2b, off, srcS, crS, ciS,
                                            (uint32_tt*)aggRb, (uint32_tt*)aggIb, N_NODES);
    gemm_mfma<128, 32, 128, 4, 1, 2, 2, false>
        <<<(N_NODES + 127) / 128, 256, 0, stream>>>(aggRb, aggIb, h2b, BT2, cb[2], lb[2],
                                                    outp, N_NODES);
}

// Round 3
// 351.685 us; speedup vs baseline: 1.7731x; 1.0270x over previous
//
#include <hip/hip_runtime.h>

#define N_NODES 50000
#define N_EDGES 600000

using bf16x8 = __attribute__((ext_vector_type(8))) short;
using f32x4  = __attribute__((ext_vector_type(4))) float;
typedef unsigned int uint32_tt;

__device__ __forceinline__ unsigned short f2bf(float f) {
    union { float f; unsigned int u; } v; v.f = f;
    unsigned int u = v.u;
    return (unsigned short)((u + 0x7fffu + ((u >> 16) & 1u)) >> 16);  // RNE
}
__device__ __forceinline__ float bf2f(unsigned int h16) {
    union { unsigned int u; float f; } v; v.u = h16 << 16;
    return v.f;
}

// ---------------- CSR build ----------------

__global__ void hist_kernel(const int* __restrict__ ei, int* __restrict__ cnt, int E) {
    int e = blockIdx.x * 256 + threadIdx.x;
    if (e < E) atomicAdd(&cnt[ei[E + e]], 1);
}

__global__ void scan1(const int* __restrict__ deg, int* __restrict__ out,
                      int* __restrict__ bsum, int n) {
    __shared__ int s[256];
    int t = threadIdx.x;
    int base = blockIdx.x * 1024 + t * 4;
    int v0 = (base + 0 < n) ? deg[base + 0] : 0;
    int v1 = (base + 1 < n) ? deg[base + 1] : 0;
    int v2 = (base + 2 < n) ? deg[base + 2] : 0;
    int v3 = (base + 3 < n) ? deg[base + 3] : 0;
    int tsum = v0 + v1 + v2 + v3;
    s[t] = tsum;
    __syncthreads();
    for (int off = 1; off < 256; off <<= 1) {
        int tmp = (t >= off) ? s[t - off] : 0;
        __syncthreads();
        s[t] += tmp;
        __syncthreads();
    }
    int excl = s[t] - tsum;
    if (base + 0 < n) out[base + 0] = excl;
    if (base + 1 < n) out[base + 1] = excl + v0;
    if (base + 2 < n) out[base + 2] = excl + v0 + v1;
    if (base + 3 < n) out[base + 3] = excl + v0 + v1 + v2;
    if (t == 255) bsum[blockIdx.x] = s[255];
}

__global__ void scan2(int* __restrict__ bsum, int nb) {
    if (threadIdx.x == 0 && blockIdx.x == 0) {
        int acc = 0;
        for (int i = 0; i < nb; ++i) { int v = bsum[i]; bsum[i] = acc; acc += v; }
    }
}

__global__ void scan3(int* __restrict__ off, const int* __restrict__ bsum, int n, int E) {
    int i = blockIdx.x * 256 + threadIdx.x;
    if (i < n) off[i] += bsum[i >> 10];
    if (i == n) off[n] = E;
}

// packed edge metadata: {src, f32bits(cr), f32bits(ci), 0} — ONE random 16B
// write stream instead of three 4B streams (write-amp 84MB -> ~line count)
__global__ void scatter_kernel(const int* __restrict__ ei, const float* __restrict__ w,
                               const float* __restrict__ sim, const int* __restrict__ off,
                               int* __restrict__ cnt, uint4* __restrict__ edat, int E) {
    int e = blockIdx.x * 256 + threadIdx.x;
    if (e >= E) return;
    int s = ei[e], d = ei[E + e];
    int p = off[d] + atomicAdd(&cnt[d], 1);
    float wt = w[e];
    uint4 m;
    m.x = (unsigned)s;
    m.y = __float_as_uint(wt * sim[2 * e]);
    m.z = __float_as_uint(wt * sim[2 * e + 1]);
    m.w = 0u;
    edat[p] = m;
}

// ---------------- prep: x -> bf16 padded [N][96]; weight pack ----------------

__global__ void convert_x(const float* __restrict__ x0, unsigned short* __restrict__ xb, int n) {
    int i = blockIdx.x * 256 + threadIdx.x;
    if (i >= n * 96) return;
    int r = i / 96, c = i - r * 96;
    xb[i] = (c < 75) ? f2bf(x0[r * 75 + c]) : (unsigned short)0;
}

// BT[n][part*CINP + k] = {wr[k][n], -wi[k][n], lw[n][k]}  (bf16, zero-padded k>=CIN)
__global__ void build_bt(const float* __restrict__ wr, const float* __restrict__ wi,
                         const float* __restrict__ lw, unsigned short* __restrict__ BT,
                         int CIN, int CINP, int COUT) {
    int KTOT = 3 * CINP;
    int i = blockIdx.x * 256 + threadIdx.x;
    if (i >= COUT * KTOT) return;
    int nn = i / KTOT, k = i - nn * KTOT;
    int part = k / CINP, kk = k - part * CINP;
    float v = 0.f;
    if (kk < CIN) {
        if (part == 0)      v = wr[kk * COUT + nn];
        else if (part == 1) v = -wi[kk * COUT + nn];
        else                v = lw[nn * CIN + kk];
    }
    BT[i] = f2bf(v);
}

// ---------------- aggregation (bf16 in/out, fp32 accum): one wave per node ----
// unroll-4: 4 independent metadata loads then 4 independent x-row gathers in
// flight before any FMA -> ~4x memory-level parallelism per wave.
template <int CU2>  // uint32s per feature row (= CINP/2)
__global__ __launch_bounds__(256) void agg_bf16(
    const uint32_tt* __restrict__ x, const int* __restrict__ off,
    const uint4* __restrict__ edat, uint32_tt* __restrict__ aggR,
    uint32_tt* __restrict__ aggI, int n) {
    int wave = threadIdx.x >> 6;
    int lane = threadIdx.x & 63;
    int node = blockIdx.x * 4 + wave;
    if (node >= n) return;
    float arl = 0.f, arh = 0.f, ail = 0.f, aih = 0.f;
    int e0 = off[node], e1 = off[node + 1];
    bool act = lane < CU2;
    int e = e0;
    for (; e + 4 <= e1; e += 4) {
        uint4 m0 = edat[e], m1 = edat[e + 1], m2 = edat[e + 2], m3 = edat[e + 3];
        uint32_tt w0 = act ? x[(size_t)m0.x * CU2 + lane] : 0u;
        uint32_tt w1 = act ? x[(size_t)m1.x * CU2 + lane] : 0u;
        uint32_tt w2 = act ? x[(size_t)m2.x * CU2 + lane] : 0u;
        uint32_tt w3 = act ? x[(size_t)m3.x * CU2 + lane] : 0u;
        float cr0 = __uint_as_float(m0.y), ci0 = __uint_as_float(m0.z);
        float cr1 = __uint_as_float(m1.y), ci1 = __uint_as_float(m1.z);
        float cr2 = __uint_as_float(m2.y), ci2 = __uint_as_float(m2.z);
        float cr3 = __uint_as_float(m3.y), ci3 = __uint_as_float(m3.z);
        float l0 = bf2f(w0 & 0xffffu), h0 = bf2f(w0 >> 16);
        float l1 = bf2f(w1 & 0xffffu), h1 = bf2f(w1 >> 16);
        float l2 = bf2f(w2 & 0xffffu), h2 = bf2f(w2 >> 16);
        float l3 = bf2f(w3 & 0xffffu), h3 = bf2f(w3 >> 16);
        arl += cr0 * l0; arh += cr0 * h0; ail += ci0 * l0; aih += ci0 * h0;
        arl += cr1 * l1; arh += cr1 * h1; ail += ci1 * l1; aih += ci1 * h1;
        arl += cr2 * l2; arh += cr2 * h2; ail += ci2 * l2; aih += ci2 * h2;
        arl += cr3 * l3; arh += cr3 * h3; ail += ci3 * l3; aih += ci3 * h3;
    }
    for (; e < e1; ++e) {
        uint4 m0 = edat[e];
        uint32_tt w0 = act ? x[(size_t)m0.x * CU2 + lane] : 0u;
        float cr0 = __uint_as_float(m0.y), ci0 = __uint_as_float(m0.z);
        float l0 = bf2f(w0 & 0xffffu), h0 = bf2f(w0 >> 16);
        arl += cr0 * l0; arh += cr0 * h0; ail += ci0 * l0; aih += ci0 * h0;
    }
    if (act) {
        aggR[(size_t)node * CU2 + lane] = (uint32_tt)f2bf(arl) | ((uint32_tt)f2bf(arh) << 16);
        aggI[(size_t)node * CU2 + lane] = (uint32_tt)f2bf(ail) | ((uint32_tt)f2bf(aih) << 16);
    }
}

// ---------------- bf16 MFMA GEMM: out = relu([aggR|aggI|x] @ BT^T + cb + lb) --
template <int CINP, int COUT, int BM, int WM, int WN, int MT, int NT, bool OUT_BF16>
__global__ __launch_bounds__(256) void gemm_mfma(
    const unsigned short* __restrict__ A0, const unsigned short* __restrict__ A1,
    const unsigned short* __restrict__ A2, const unsigned short* __restrict__ BT,
    const float* __restrict__ cb, const float* __restrict__ lb,
    void* __restrict__ outv, int n) {
    constexpr int PK = 40;              // padded k-stride (bf16): 80B rows -> 2-way banks
    constexpr int KTOT = 3 * CINP;
    constexpr int NCH = KTOT / 32;      // K chunks
    constexpr int CPP = CINP / 32;      // chunks per part
    __shared__ unsigned short sA[BM][PK];
    __shared__ unsigned short sB[COUT][PK];

    int t = threadIdx.x;
    int lane = t & 63, wave = t >> 6;
    int wm = wave / WN, wn = wave % WN;
    int ml = lane & 15, kh = lane >> 4;   // kh in [0,4)
    int node0 = blockIdx.x * BM;

    const unsigned short* Asrc[3] = {A0, A1, A2};

    f32x4 acc[MT][NT];
#pragma unroll
    for (int mt = 0; mt < MT; ++mt)
#pragma unroll
        for (int nt = 0; nt < NT; ++nt) acc[mt][nt] = (f32x4){0.f, 0.f, 0.f, 0.f};

    for (int c = 0; c < NCH; ++c) {
        int part = c / CPP;
        int kk = (c - part * CPP) * 32;
        const unsigned short* __restrict__ Ap = Asrc[part];
        __syncthreads();
#pragma unroll
        for (int i = t; i < BM * 4; i += 256) {
            int r = i >> 2, q = i & 3;
            int node = node0 + r;
            if (node >= n) node = n - 1;  // clamp: garbage rows never written out
            *(uint4*)&sA[r][q * 8] =
                *(const uint4*)(Ap + (size_t)node * CINP + kk + q * 8);
        }
#pragma unroll
        for (int i = t; i < COUT * 4; i += 256) {
            int r = i >> 2, q = i & 3;
            *(uint4*)&sB[r][q * 8] =
                *(const uint4*)(BT + (size_t)r * KTOT + c * 32 + q * 8);
        }
        __syncthreads();
        bf16x8 af[MT], bfr[NT];
#pragma unroll
        for (int mt = 0; mt < MT; ++mt)
            af[mt] = *(const bf16x8*)&sA[wm * (MT * 16) + mt * 16 + ml][kh * 8];
#pragma unroll
        for (int nt = 0; nt < NT; ++nt)
            bfr[nt] = *(const bf16x8*)&sB[wn * (NT * 16) + nt * 16 + ml][kh * 8];
#pragma unroll
        for (int mt = 0; mt < MT; ++mt)
#pragma unroll
            for (int nt = 0; nt < NT; ++nt)
                acc[mt][nt] = __builtin_amdgcn_mfma_f32_16x16x32_bf16(
                    af[mt], bfr[nt], acc[mt][nt], 0, 0, 0);
    }

    // epilogue: C/D layout col=lane&15, row=(lane>>4)*4+reg  [m89-verified]
    int row0 = kh * 4;
#pragma unroll
    for (int nt = 0; nt < NT; ++nt) {
        int col = wn * (NT * 16) + nt * 16 + ml;
        float bias = cb[col] + lb[col];
#pragma unroll
        for (int mt = 0; mt < MT; ++mt) {
#pragma unroll
            for (int r = 0; r < 4; ++r) {
                int node = node0 + wm * (MT * 16) + mt * 16 + row0 + r;
                if (node < n) {
                    float v = acc[mt][nt][r] + bias;
                    v = v > 0.f ? v : 0.f;
                    if (OUT_BF16)
                        ((unsigned short*)outv)[(size_t)node * COUT + col] = f2bf(v);
                    else
                        ((float*)outv)[(size_t)node * COUT + col] = v;
                }
            }
        }
    }
}

// ---------------- launch ----------------

extern "C" void kernel_launch(void* const* d_in, const int* in_sizes, int n_in,
                              void* d_out, int out_size, void* d_ws, size_t ws_size,
                              hipStream_t stream) {
    const float* x0  = (const float*)d_in[0];
    const int*   ei  = (const int*)d_in[1];
    const float* wgt = (const float*)d_in[2];
    const float* sim = (const float*)d_in[3];
    const float *wr[3], *wi[3], *cb[3], *lw[3], *lb[3];
    for (int l = 0; l < 3; ++l) {
        wr[l] = (const float*)d_in[4 + 5 * l];
        wi[l] = (const float*)d_in[5 + 5 * l];
        cb[l] = (const float*)d_in[6 + 5 * l];
        lw[l] = (const float*)d_in[7 + 5 * l];
        lb[l] = (const float*)d_in[8 + 5 * l];
    }

    char* p = (char*)d_ws;
    auto alloc = [&](size_t bytes) -> void* {
        void* r = p;
        p += (bytes + 255) & ~(size_t)255;
        return r;
    };
    int*   off  = (int*)alloc((N_NODES + 1) * 4);
    int*   cnt  = (int*)alloc(N_NODES * 4);
    int*   bsum = (int*)alloc(256);
    uint4* edat = (uint4*)alloc((size_t)N_EDGES * 16);
    unsigned short* xb    = (unsigned short*)alloc((size_t)N_NODES * 96 * 2);
    unsigned short* aggRb = (unsigned short*)alloc((size_t)N_NODES * 128 * 2);
    unsigned short* aggIb = (unsigned short*)alloc((size_t)N_NODES * 128 * 2);
    unsigned short* h1b   = (unsigned short*)alloc((size_t)N_NODES * 128 * 2);
    unsigned short* h2b   = (unsigned short*)alloc((size_t)N_NODES * 128 * 2);
    unsigned short* BT0   = (unsigned short*)alloc((size_t)128 * 288 * 2);
    unsigned short* BT1   = (unsigned short*)alloc((size_t)128 * 384 * 2);
    unsigned short* BT2   = (unsigned short*)alloc((size_t)32 * 384 * 2);
    float* outp = (float*)d_out;

    // CSR build
    hipMemsetAsync(cnt, 0, N_NODES * 4, stream);
    hist_kernel<<<(N_EDGES + 255) / 256, 256, 0, stream>>>(ei, cnt, N_EDGES);
    int nb = (N_NODES + 1023) / 1024;
    scan1<<<nb, 256, 0, stream>>>(cnt, off, bsum, N_NODES);
    scan2<<<1, 64, 0, stream>>>(bsum, nb);
    scan3<<<(N_NODES + 1 + 255) / 256, 256, 0, stream>>>(off, bsum, N_NODES, N_EDGES);
    hipMemsetAsync(cnt, 0, N_NODES * 4, stream);
    scatter_kernel<<<(N_EDGES + 255) / 256, 256, 0, stream>>>(ei, wgt, sim, off, cnt,
                                                              edat, N_EDGES);
    // prep
    convert_x<<<(N_NODES * 96 + 255) / 256, 256, 0, stream>>>(x0, xb, N_NODES);
    build_bt<<<(128 * 288 + 255) / 256, 256, 0, stream>>>(wr[0], wi[0], lw[0], BT0, 75, 96, 128);
    build_bt<<<(128 * 384 + 255) / 256, 256, 0, stream>>>(wr[1], wi[1], lw[1], BT1, 128, 128, 128);
    build_bt<<<(32 * 384 + 255) / 256, 256, 0, stream>>>(wr[2], wi[2], lw[2], BT2, 128, 128, 32);

    int agrid = (N_NODES + 3) / 4;

    // layer 0: xb [N,96] -> h1b [N,128]
    agg_bf16<48><<<agrid, 256, 0, stream>>>((const uint32_tt*)xb, off, edat,
                                            (uint32_tt*)aggRb, (uint32_tt*)aggIb, N_NODES);
    gemm_mfma<96, 128, 64, 2, 2, 2, 4, true>
        <<<(N_NODES + 63) / 64, 256, 0, stream>>>(aggRb, aggIb, xb, BT0, cb[0], lb[0],
                                                  h1b, N_NODES);
    // layer 1: h1b [N,128] -> h2b [N,128]
    agg_bf16<64><<<agrid, 256, 0, stream>>>((const uint32_tt*)h1b, off, edat,
                                            (uint32_tt*)aggRb, (uint32_tt*)aggIb, N_NODES);
    gemm_mfma<128, 128, 64, 2, 2, 2, 4, true>
        <<<(N_NODES + 63) / 64, 256, 0, stream>>>(aggRb, aggIb, h1b, BT1, cb[1], lb[1],
                                                  h2b, N_NODES);
    // layer 2: h2b [N,128] -> out [N,32] fp32
    agg_bf16<64><<<agrid, 256, 0, stream>>>((const uint32_tt*)h2b, off, edat,
                                            (uint32_tt*)aggRb, (uint32_tt*)aggIb, N_NODES);
    gemm_mfma<128, 32, 128, 4, 1, 2, 2, false>
        <<<(N_NODES + 127) / 128, 256, 0, stream>>>(aggRb, aggIb, h2b, BT2, cb[2], lb[2],
                                                    outp, N_NODES);
}